// Round 6
// baseline (1039.678 us; speedup 1.0000x reference)
//
#include <hip/hip_runtime.h>

// DerivNet2D fused MLP + forward-mode derivatives, v5.
// Same 8-phase software-pipelined schedule as v4, but fragment double-buffers
// are value-semantics structs (no address-taken arrays -> no scratch spill).

#define NXS    65536
#define SB     32
#define NBLK   2048        // NXS / SB
#define KSTEPS 8           // K=1024 / 128

typedef short bh8_t __attribute__((ext_vector_type(8)));    // 8 x bf16
typedef unsigned int u32x4 __attribute__((ext_vector_type(4)));
typedef float fx16_t __attribute__((ext_vector_type(16)));  // 32x32 accum
typedef unsigned int u32;

struct Afrag { bh8_t a0, a1, a2; };
struct Bfrag { bh8_t b0, b1, b2, b3; };

static __device__ __forceinline__ unsigned short f2bf(float f) {
  u32 u = __builtin_bit_cast(u32, f);
  u += 0x7FFFu + ((u >> 16) & 1u);      // RNE (prep kernel only)
  return (unsigned short)(u >> 16);
}

static __device__ __forceinline__ u32 pkbf(float lo, float hi) {
  u32 r;
  asm("v_cvt_pk_bf16_f32 %0, %1, %2" : "=v"(r) : "v"(lo), "v"(hi));
  return r;
}

static __device__ __forceinline__ float fast_tanh(float h) {
  float e = __expf(2.0f * h);
  return 1.0f - 2.0f / (e + 1.0f);
}

// prep: (a) W2 fp32 [512][1024] -> fragment-major bf16 frags
//   f = ((kblock*16 + nbk)*64 + q*32 + col), 16B each, holding
//   W2[n = nbk*32+col][k = 16*kblock + {4q..4q+3, 8+4q..8+4q+3}].
// (b) W1b[k] = {W1[k][0], W1[k][1], b1[k], 0} packed float4.
__global__ void prep_all(const float* __restrict__ W2, const float* __restrict__ W1,
                         const float* __restrict__ b1, bh8_t* __restrict__ W2pT,
                         float4* __restrict__ W1b) {
  int f = blockIdx.x * 256 + threadIdx.x;      // 0..65535
  int col = f & 31;
  int q   = (f >> 5) & 1;
  int nbk = (f >> 6) & 15;
  int kb  = f >> 10;
  const float* row = W2 + (nbk * 32 + col) * 1024 + kb * 16 + 4 * q;
  float4 lo = *(const float4*)(row);
  float4 hi = *(const float4*)(row + 8);
  bh8_t o;
  o[0] = (short)f2bf(lo.x); o[1] = (short)f2bf(lo.y);
  o[2] = (short)f2bf(lo.z); o[3] = (short)f2bf(lo.w);
  o[4] = (short)f2bf(hi.x); o[5] = (short)f2bf(hi.y);
  o[6] = (short)f2bf(hi.z); o[7] = (short)f2bf(hi.w);
  W2pT[f] = o;
  if (f < 1024) {
    float2 w = *(const float2*)(W1 + 2 * f);
    W1b[f] = make_float4(w.x, w.y, b1[f], 0.0f);
  }
}

__global__ __launch_bounds__(256, 2) void fused_kernel(
    const float* __restrict__ x,  const float4* __restrict__ W1b,
    const float* __restrict__ b2, const float* __restrict__ W3,
    const float* __restrict__ b3, const bh8_t* __restrict__ Bg,
    float* __restrict__ out)
{
  __shared__ __attribute__((aligned(16))) char smem[49152 + 1536];
  const int tid  = threadIdx.x;
  const int lane = tid & 63;
  const int wave = tid >> 6;        // 0..3, owns N cols [128w, 128w+128)
  const int q    = lane >> 5;
  const int col  = lane & 31;
  const int s0   = blockIdx.x * SB;

  // A-gen role: gs = sample, gkb = 16-k block 0..7
  const int gs  = tid & 31;
  const int gkb = tid >> 5;
  const float2 xv = *(const float2*)(x + 2 * (s0 + gs));
  const float x0 = xv.x, x1 = xv.y;
  const int wbase = (gs * 256) | (((gkb << 1) ^ (gs & 7)) << 4);  // gqp=0 unit

  // epilogue constants preloaded (overlaps with prologue latency)
  float b2n[4], w3n[4];
#pragma unroll
  for (int nb = 0; nb < 4; ++nb) {
    int n = wave * 128 + nb * 32 + col;
    b2n[nb] = b2[n];
    w3n[nb] = W3[n];
  }

  fx16_t acc[3][4];
#pragma unroll
  for (int b = 0; b < 3; ++b)
#pragma unroll
    for (int nb = 0; nb < 4; ++nb)
#pragma unroll
      for (int r = 0; r < 16; ++r) acc[b][nb][r] = 0.0f;

  u32x4 sz, sv0, sv1;          // staging accumulators (one 16B unit x 3 bands)

  auto loadB = [&](int kt, int ks) -> Bfrag {
    const int fb = ((kt * 8 + ks) * 16 + wave * 4) * 64 + lane;
    Bfrag f;
    f.b0 = Bg[fb];
    f.b1 = Bg[fb + 64];
    f.b2 = Bg[fb + 128];
    f.b3 = Bg[fb + 192];
    return f;
  };
  auto loadA = [&](const char* Ab, int ks) -> Afrag {
    const int uoff = (((2 * ks + q) ^ (col & 7)) << 4);
    const char* p = Ab + col * 256 + uoff;
    Afrag f;
    f.a0 = *(const bh8_t*)(p);
    f.a1 = *(const bh8_t*)(p + 8192);
    f.a2 = *(const bh8_t*)(p + 16384);
    return f;
  };
  // phase p in 0..7: gqp=p>>2, jp=(p>>1)&1, half=p&1 -> one u32 (2 tanh) per band;
  // unit flush (16B x 3 bands) at p==3 and p==7.
  auto stage_pair = [&](int ktA, char* Ab, int p) {
    const int gqp = p >> 2, jp = (p >> 1) & 1, half = p & 1;
    const int k0 = ktA * 128 + gkb * 16 + gqp * 4 + half * 8 + 2 * jp;
    float4 cA = W1b[k0];
    float4 cB = W1b[k0 + 1];
    float hA = fmaf(x0, cA.x, fmaf(x1, cA.y, cA.z));
    float hB = fmaf(x0, cB.x, fmaf(x1, cB.y, cB.z));
    float zA = fast_tanh(hA), zB = fast_tanh(hB);
    float dA = 1.f - zA * zA, dB = 1.f - zB * zB;
    const int slot = half * 2 + jp;
    sz[slot]  = pkbf(zA, zB);
    sv0[slot] = pkbf(dA * cA.x, dB * cB.x);
    sv1[slot] = pkbf(dA * cA.y, dB * cB.y);
    if ((p & 3) == 3) {
      char* dst = Ab + (wbase ^ (gqp << 4));
      *(u32x4*)(dst)         = sz;
      *(u32x4*)(dst + 8192)  = sv0;
      *(u32x4*)(dst + 16384) = sv1;
    }
  };
  auto mfma12 = [&](const Afrag& A, const Bfrag& B) {
    __builtin_amdgcn_s_setprio(1);
    acc[0][0] = __builtin_amdgcn_mfma_f32_32x32x16_bf16(A.a0, B.b0, acc[0][0], 0, 0, 0);
    acc[1][0] = __builtin_amdgcn_mfma_f32_32x32x16_bf16(A.a1, B.b0, acc[1][0], 0, 0, 0);
    acc[2][0] = __builtin_amdgcn_mfma_f32_32x32x16_bf16(A.a2, B.b0, acc[2][0], 0, 0, 0);
    acc[0][1] = __builtin_amdgcn_mfma_f32_32x32x16_bf16(A.a0, B.b1, acc[0][1], 0, 0, 0);
    acc[1][1] = __builtin_amdgcn_mfma_f32_32x32x16_bf16(A.a1, B.b1, acc[1][1], 0, 0, 0);
    acc[2][1] = __builtin_amdgcn_mfma_f32_32x32x16_bf16(A.a2, B.b1, acc[2][1], 0, 0, 0);
    acc[0][2] = __builtin_amdgcn_mfma_f32_32x32x16_bf16(A.a0, B.b2, acc[0][2], 0, 0, 0);
    acc[1][2] = __builtin_amdgcn_mfma_f32_32x32x16_bf16(A.a1, B.b2, acc[1][2], 0, 0, 0);
    acc[2][2] = __builtin_amdgcn_mfma_f32_32x32x16_bf16(A.a2, B.b2, acc[2][2], 0, 0, 0);
    acc[0][3] = __builtin_amdgcn_mfma_f32_32x32x16_bf16(A.a0, B.b3, acc[0][3], 0, 0, 0);
    acc[1][3] = __builtin_amdgcn_mfma_f32_32x32x16_bf16(A.a1, B.b3, acc[1][3], 0, 0, 0);
    acc[2][3] = __builtin_amdgcn_mfma_f32_32x32x16_bf16(A.a2, B.b3, acc[2][3], 0, 0, 0);
    __builtin_amdgcn_s_setprio(0);
  };

  // === prologue: B[0][0] in flight, then full stage of kt=0 ===
  Bfrag Bc = loadB(0, 0);
#pragma unroll
  for (int p = 0; p < 8; ++p) stage_pair(0, smem, p);
  __syncthreads();
  Afrag Ac = loadA(smem, 0);

  for (int kt = 0; kt < KSTEPS; ++kt) {
    char* Acur = smem + (kt & 1) * 24576;
    char* Anxt = smem + ((kt + 1) & 1) * 24576;
    const bool more = (kt + 1 < KSTEPS);
#pragma unroll
    for (int ks = 0; ks < 8; ++ks) {
      Afrag An;
      Bfrag Bn;
      if (ks < 7) {
        Bn = loadB(kt, ks + 1);           // longest latency first
        An = loadA(Acur, ks + 1);
      } else if (more) {
        Bn = loadB(kt + 1, 0);            // crosses the barrier legally
      }
      if (more) stage_pair(kt + 1, Anxt, ks);   // VALU fills the load shadow
      mfma12(Ac, Bc);                     // regs issued one phase ago
      Bc = Bn;
      if (ks < 7) Ac = An;
    }
    __syncthreads();
    if (more) Ac = loadA(Anxt, 0);        // first A of next kt
  }

  // Epilogue: z2 = tanh(h2+b2), d2 = 1-z2^2; weighted reduce over n with W3.
  float* P = (float*)(smem + 49152);   // [3][32 samples][4 waves]
#pragma unroll
  for (int r = 0; r < 16; ++r) {
    const int srow_o = (r & 3) + 8 * (r >> 2) + 4 * q;   // sample 0..31
    float py = 0.f, p1 = 0.f, p2 = 0.f;
#pragma unroll
    for (int nb = 0; nb < 4; ++nb) {
      float z2 = fast_tanh(acc[0][nb][r] + b2n[nb]);
      float d2 = 1.f - z2 * z2;
      py = fmaf(w3n[nb], z2, py);
      p1 = fmaf(w3n[nb] * d2, acc[1][nb][r], p1);
      p2 = fmaf(w3n[nb] * d2, acc[2][nb][r], p2);
    }
#pragma unroll
    for (int m = 1; m < 32; m <<= 1) {
      py += __shfl_xor(py, m, 64);
      p1 += __shfl_xor(p1, m, 64);
      p2 += __shfl_xor(p2, m, 64);
    }
    if (col == 0) {
      P[0 * 128 + srow_o * 4 + wave] = py;
      P[1 * 128 + srow_o * 4 + wave] = p1;
      P[2 * 128 + srow_o * 4 + wave] = p2;
    }
  }
  __syncthreads();
  if (tid < 96) {
    const int v = tid >> 5, s = tid & 31;
    const float* Pv = P + v * 128 + s * 4;
    float sum = Pv[0] + Pv[1] + Pv[2] + Pv[3];
    const int si = s0 + s;
    if (v == 0)      out[si]           = sum + b3[0];  // y
    else if (v == 2) out[NXS + si]     = sum;          // v1 = dydx2
    else             out[2 * NXS + si] = -sum;         // v2 = -dydx1
  }
}

extern "C" void kernel_launch(void* const* d_in, const int* in_sizes, int n_in,
                              void* d_out, int out_size, void* d_ws, size_t ws_size,
                              hipStream_t stream) {
  const float* x  = (const float*)d_in[0];
  const float* W1 = (const float*)d_in[1];
  const float* b1 = (const float*)d_in[2];
  const float* W2 = (const float*)d_in[3];
  const float* b2 = (const float*)d_in[4];
  const float* W3 = (const float*)d_in[5];
  const float* b3 = (const float*)d_in[6];
  bh8_t*  W2pT = (bh8_t*)d_ws;                         // 1 MB fragment-major bf16 W2
  float4* W1b  = (float4*)((char*)d_ws + (1 << 20));   // packed {w0,w1,b1} table

  prep_all<<<256, 256, 0, stream>>>(W2, W1, b1, W2pT, W1b);
  fused_kernel<<<NBLK, 256, 0, stream>>>(
      x, W1b, b2, W3, b3, (const bh8_t*)W2pT, (float*)d_out);
}

// Round 7
// 339.204 us; speedup vs baseline: 3.0651x; 3.0651x over previous
//
#include <hip/hip_runtime.h>

// DerivNet2D, v6: reverse-mode restructure.
// Per block (32 samples, 512 threads = 8 waves, 1 block/CU):
//   phase0: z1[32][1024] bf16 -> LDS (A-operand layout, XOR-swizzled)
//   GEMM1 : h2 = z1 @ W2^T     (M=32,N=512,K=1024)  acc1[2]/wave
//   epi1  : z2=tanh(h2+b2); y-partials; e = W3*(1-z2^2) packed -> A2 LDS tile
//   GEMM2 : c = e @ W2         (M=32,N=1024,K=512)  acc2[4]/wave
//   epi2  : dydx_j = sum_k1 c*d1*W1[:,j], d1 = 1 - z1^2 (z1 re-read from LDS)
// W2 prepped to TWO fragment-major bf16 copies (k-contraction and n-contraction).

#define NXS  65536
#define SB   32
#define NBLK 2048

typedef short bh8_t __attribute__((ext_vector_type(8)));
typedef unsigned int u32x4 __attribute__((ext_vector_type(4)));
typedef float fx16_t __attribute__((ext_vector_type(16)));
typedef unsigned int u32;

struct B1set { bh8_t b0, b1; };
struct B2set { bh8_t b0, b1, b2, b3; };

#define LDS_Z1 0          // [32][1024] bf16, interleaved+swizzled: 65536 B
#define LDS_A2 65536      // [32][512]  bf16, same recipe:          32768 B
#define LDS_P  98304      // [3][32][8] f32 partials:                3072 B
#define LDS_TOTAL 101376

static __device__ __forceinline__ unsigned short f2bf(float f) {
  u32 u = __builtin_bit_cast(u32, f);
  u += 0x7FFFu + ((u >> 16) & 1u);
  return (unsigned short)(u >> 16);
}
static __device__ __forceinline__ float bf2f(unsigned short h) {
  u32 u = ((u32)h) << 16;
  return __builtin_bit_cast(float, u);
}
static __device__ __forceinline__ u32 pkbf(float lo, float hi) {
  u32 r;
  asm("v_cvt_pk_bf16_f32 %0, %1, %2" : "=v"(r) : "v"(lo), "v"(hi));
  return r;
}
static __device__ __forceinline__ float fast_tanh(float h) {
  float e = __expf(2.0f * h);
  return 1.0f - 2.0f / (e + 1.0f);
}

// W2pT  (GEMM1 B): f = (kb*16 + nbk)*64 + lane, holds W2[n=nbk*32+col][k=16kb+{4q+j,8+4q+j}]
// W2TpT (GEMM2 B): f = (ks2*32 + nbk2)*64 + lane, holds W2[n=16ks2+{4q+j,8+4q+j}][k1=nbk2*32+col]
// W1b[k] = {W1[k][0], W1[k][1], b1[k], 0}
__global__ void prep_all(const float* __restrict__ W2, const float* __restrict__ W1,
                         const float* __restrict__ b1, bh8_t* __restrict__ W2pT,
                         bh8_t* __restrict__ W2TpT, float4* __restrict__ W1b) {
  int id = blockIdx.x * 256 + threadIdx.x;   // 0..131071
  if (id < 65536) {
    int col = id & 31, q = (id >> 5) & 1, nbk = (id >> 6) & 15, kb = id >> 10;
    const float* row = W2 + (nbk * 32 + col) * 1024 + kb * 16 + 4 * q;
    float4 lo = *(const float4*)(row);
    float4 hi = *(const float4*)(row + 8);
    bh8_t o;
    o[0] = (short)f2bf(lo.x); o[1] = (short)f2bf(lo.y);
    o[2] = (short)f2bf(lo.z); o[3] = (short)f2bf(lo.w);
    o[4] = (short)f2bf(hi.x); o[5] = (short)f2bf(hi.y);
    o[6] = (short)f2bf(hi.z); o[7] = (short)f2bf(hi.w);
    W2pT[id] = o;
    if (id < 1024) {
      float2 w = *(const float2*)(W1 + 2 * id);
      W1b[id] = make_float4(w.x, w.y, b1[id], 0.0f);
    }
  } else {
    int f = id - 65536;
    int col = f & 31, q = (f >> 5) & 1, nbk2 = (f >> 6) & 31, ks2 = f >> 11;
    int k1 = nbk2 * 32 + col;
    bh8_t o;
#pragma unroll
    for (int j = 0; j < 8; ++j) {
      int n = ks2 * 16 + (j < 4 ? 4 * q + j : 4 + 4 * q + j);   // {4q..4q+3, 8+4q..8+4q+3}
      o[j] = (short)f2bf(W2[n * 1024 + k1]);
    }
    W2TpT[f] = o;
  }
}

__global__ __launch_bounds__(512, 2) void fused_kernel(
    const float* __restrict__ x,  const float4* __restrict__ W1b,
    const float* __restrict__ b2, const float* __restrict__ W3,
    const float* __restrict__ b3, const bh8_t* __restrict__ Bg1,
    const bh8_t* __restrict__ Bg2, float* __restrict__ out)
{
  extern __shared__ __attribute__((aligned(16))) char sm[];
  const int tid  = threadIdx.x;
  const int lane = tid & 63;
  const int wave = tid >> 6;        // 0..7
  const int q    = lane >> 5;
  const int col  = lane & 31;
  const int s0   = blockIdx.x * SB;

  // epilogue1 constants: n = wave*64 + nb*32 + col
  float b2n[2], w3n[2];
#pragma unroll
  for (int nb = 0; nb < 2; ++nb) {
    int n = wave * 64 + nb * 32 + col;
    b2n[nb] = b2[n];
    w3n[nb] = W3[n];
  }

  auto loadB1 = [&](int ks) -> B1set {
    const int fb = (ks * 16 + wave * 2) * 64 + lane;
    B1set r; r.b0 = Bg1[fb]; r.b1 = Bg1[fb + 64]; return r;
  };
  auto loadA1 = [&](int ks) -> bh8_t {
    return *(const bh8_t*)(sm + LDS_Z1 + col * 2048 + ((((ks << 1) + q) ^ (col & 7)) << 4));
  };
  auto loadB2 = [&](int ks2) -> B2set {
    const int fb = (ks2 * 32 + wave * 4) * 64 + lane;
    B2set r; r.b0 = Bg2[fb]; r.b1 = Bg2[fb + 64]; r.b2 = Bg2[fb + 128]; r.b3 = Bg2[fb + 192];
    return r;
  };
  auto loadA2 = [&](int ks2) -> bh8_t {
    return *(const bh8_t*)(sm + LDS_A2 + col * 1024 + ((((ks2 << 1) + q) ^ (col & 7)) << 4));
  };

  // B1 prefetch rides under z1-gen
  B1set Bc = loadB1(0), Bn = loadB1(1), Bn2 = loadB1(2);

  // ===== phase 0: z1 generation -> LDS =====
  {
    const int gs  = tid & 31;
    const int kb4 = tid >> 5;       // 0..15, covers kblocks kb4*4 .. kb4*4+3
    const float2 xv = *(const float2*)(x + 2 * (s0 + gs));
    const float x0 = xv.x, x1 = xv.y;
#pragma unroll
    for (int i = 0; i < 4; ++i) {
      const int gkb = kb4 * 4 + i;
#pragma unroll
      for (int gqp = 0; gqp < 2; ++gqp) {
        const int k0 = gkb * 16 + 4 * gqp;
        u32x4 wz;
#pragma unroll
        for (int jp = 0; jp < 2; ++jp) {
          float4 cA = W1b[k0 + 2 * jp];
          float4 cB = W1b[k0 + 2 * jp + 1];
          float4 cC = W1b[k0 + 8 + 2 * jp];
          float4 cD = W1b[k0 + 8 + 2 * jp + 1];
          float zA = fast_tanh(fmaf(x0, cA.x, fmaf(x1, cA.y, cA.z)));
          float zB = fast_tanh(fmaf(x0, cB.x, fmaf(x1, cB.y, cB.z)));
          float zC = fast_tanh(fmaf(x0, cC.x, fmaf(x1, cC.y, cC.z)));
          float zD = fast_tanh(fmaf(x0, cD.x, fmaf(x1, cD.y, cD.z)));
          wz[jp]     = pkbf(zA, zB);
          wz[2 + jp] = pkbf(zC, zD);
        }
        *(u32x4*)(sm + LDS_Z1 + gs * 2048 +
                  ((((gkb << 1) + gqp) ^ (gs & 7)) << 4)) = wz;
      }
    }
  }
  __syncthreads();

  // ===== GEMM1: h2 = z1 @ W2^T =====
  fx16_t acc1[2];
#pragma unroll
  for (int nb = 0; nb < 2; ++nb)
#pragma unroll
    for (int r = 0; r < 16; ++r) acc1[nb][r] = 0.0f;

  bh8_t Ac = loadA1(0), An = loadA1(1);
#pragma unroll
  for (int ks = 0; ks < 64; ++ks) {
    B1set Bn3{};
    bh8_t An2{};
    if (ks + 3 < 64) Bn3 = loadB1(ks + 3);
    if (ks + 2 < 64) An2 = loadA1(ks + 2);
    __builtin_amdgcn_s_setprio(1);
    acc1[0] = __builtin_amdgcn_mfma_f32_32x32x16_bf16(Ac, Bc.b0, acc1[0], 0, 0, 0);
    acc1[1] = __builtin_amdgcn_mfma_f32_32x32x16_bf16(Ac, Bc.b1, acc1[1], 0, 0, 0);
    __builtin_amdgcn_s_setprio(0);
    Bc = Bn; Bn = Bn2; Bn2 = Bn3; Ac = An; An = An2;
  }

  // B2 prefetch rides under epilogue1
  B2set Cc = loadB2(0), Cn = loadB2(1), Cn2 = loadB2(2);

  // ===== epilogue1: z2, y-partials, e -> A2 tile =====
  float* Pf = (float*)(sm + LDS_P);
#pragma unroll
  for (int r = 0; r < 16; ++r) {
    const int s = (r & 3) + 8 * (r >> 2) + 4 * q;
    float py = 0.f;
#pragma unroll
    for (int nb = 0; nb < 2; ++nb) {
      float z2 = fast_tanh(acc1[nb][r] + b2n[nb]);
      py = fmaf(w3n[nb], z2, py);
      float e = w3n[nb] * (1.f - z2 * z2);
      float ep = __shfl_xor(e, 1, 64);
      u32 pk = (col & 1) ? pkbf(ep, e) : pkbf(e, ep);
      if ((col & 1) == (r >> 3)) {           // even cols: r<8, odd cols: r>=8
        const int n = wave * 64 + nb * 32 + col;
        const int u_idx = (((n >> 4) << 1) + ((n >> 2) & 1)) ^ (s & 7);
        const int wd = ((n >> 1) & 1) + 2 * ((n >> 3) & 1);
        *(u32*)(sm + LDS_A2 + s * 1024 + (u_idx << 4) + wd * 4) = pk;
      }
    }
#pragma unroll
    for (int m = 1; m < 32; m <<= 1) py += __shfl_xor(py, m, 64);
    if (col == 0) Pf[0 * 256 + s * 8 + wave] = py;
  }
  __syncthreads();

  // ===== GEMM2: c = e @ W2 =====
  fx16_t acc2[4];
#pragma unroll
  for (int nb = 0; nb < 4; ++nb)
#pragma unroll
    for (int r = 0; r < 16; ++r) acc2[nb][r] = 0.0f;

  bh8_t Ec = loadA2(0), En = loadA2(1);
#pragma unroll
  for (int ks2 = 0; ks2 < 32; ++ks2) {
    B2set Cn3{};
    bh8_t En2{};
    if (ks2 + 3 < 32) Cn3 = loadB2(ks2 + 3);
    if (ks2 + 2 < 32) En2 = loadA2(ks2 + 2);
    __builtin_amdgcn_s_setprio(1);
    acc2[0] = __builtin_amdgcn_mfma_f32_32x32x16_bf16(Ec, Cc.b0, acc2[0], 0, 0, 0);
    acc2[1] = __builtin_amdgcn_mfma_f32_32x32x16_bf16(Ec, Cc.b1, acc2[1], 0, 0, 0);
    acc2[2] = __builtin_amdgcn_mfma_f32_32x32x16_bf16(Ec, Cc.b2, acc2[2], 0, 0, 0);
    acc2[3] = __builtin_amdgcn_mfma_f32_32x32x16_bf16(Ec, Cc.b3, acc2[3], 0, 0, 0);
    __builtin_amdgcn_s_setprio(0);
    Cc = Cn; Cn = Cn2; Cn2 = Cn3; Ec = En; En = En2;
  }

  // ===== epilogue2: dydx_j = sum_k1 c * d1 * W1[:,j] =====
  float w0c[4], w1c[4];
#pragma unroll
  for (int nb = 0; nb < 4; ++nb) {
    const int k1 = wave * 128 + nb * 32 + col;
    float4 c = W1b[k1];
    w0c[nb] = c.x; w1c[nb] = c.y;
  }
#pragma unroll
  for (int r = 0; r < 16; ++r) {
    const int s = (r & 3) + 8 * (r >> 2) + 4 * q;
    float p1 = 0.f, p2 = 0.f;
#pragma unroll
    for (int nb = 0; nb < 4; ++nb) {
      const int k1 = wave * 128 + nb * 32 + col;
      const int kil = k1 & 15;
      const int u_idx = ((((k1 >> 4) << 1) + ((kil >> 2) & 1)) ^ (s & 7));
      const int sidx = (kil & 3) + 4 * (kil >> 3);
      float z1 = bf2f(*(const unsigned short*)(sm + LDS_Z1 + s * 2048 + (u_idx << 4) + sidx * 2));
      float cd = acc2[nb][r] * (1.f - z1 * z1);
      p1 = fmaf(cd, w0c[nb], p1);
      p2 = fmaf(cd, w1c[nb], p2);
    }
#pragma unroll
    for (int m = 1; m < 32; m <<= 1) {
      p1 += __shfl_xor(p1, m, 64);
      p2 += __shfl_xor(p2, m, 64);
    }
    if (col == 0) {
      Pf[1 * 256 + s * 8 + wave] = p1;
      Pf[2 * 256 + s * 8 + wave] = p2;
    }
  }
  __syncthreads();

  if (tid < 96) {
    const int v = tid >> 5, s = tid & 31;
    const float* Pv = Pf + v * 256 + s * 8;
    float sum = ((Pv[0] + Pv[1]) + (Pv[2] + Pv[3])) + ((Pv[4] + Pv[5]) + (Pv[6] + Pv[7]));
    const int si = s0 + s;
    if (v == 0)      out[si]           = sum + b3[0];  // y
    else if (v == 2) out[NXS + si]     = sum;          // v1 = dydx2
    else             out[2 * NXS + si] = -sum;         // v2 = -dydx1
  }
}

extern "C" void kernel_launch(void* const* d_in, const int* in_sizes, int n_in,
                              void* d_out, int out_size, void* d_ws, size_t ws_size,
                              hipStream_t stream) {
  const float* x  = (const float*)d_in[0];
  const float* W1 = (const float*)d_in[1];
  const float* b1 = (const float*)d_in[2];
  const float* W2 = (const float*)d_in[3];
  const float* b2 = (const float*)d_in[4];
  const float* W3 = (const float*)d_in[5];
  const float* b3 = (const float*)d_in[6];
  bh8_t*  W2pT  = (bh8_t*)d_ws;                         // 1 MB
  bh8_t*  W2TpT = (bh8_t*)((char*)d_ws + (1 << 20));    // 1 MB
  float4* W1b   = (float4*)((char*)d_ws + (2 << 20));   // 16 KB

  prep_all<<<512, 256, 0, stream>>>(W2, W1, b1, W2pT, W2TpT, W1b);

  (void)hipFuncSetAttribute(reinterpret_cast<const void*>(fused_kernel),
                            hipFuncAttributeMaxDynamicSharedMemorySize, LDS_TOTAL);
  fused_kernel<<<NBLK, 512, LDS_TOTAL, stream>>>(
      x, W1b, b2, W3, b3, (const bh8_t*)W2pT, (const bh8_t*)W2TpT, (float*)d_out);
}